// Round 7
// baseline (3579.450 us; speedup 1.0000x reference)
//
#include <hip/hip_runtime.h>

#define DI __device__ __forceinline__

typedef __attribute__((ext_vector_type(2))) float f32x2;
typedef __attribute__((ext_vector_type(4))) float f32x4;
typedef __attribute__((ext_vector_type(8))) short bf16x8;
typedef __attribute__((ext_vector_type(8))) unsigned short u16x8;

constexpr int Vv = 50257, NPAD = 50304, Ee = 512, Hh = 512, Bb = 16, TDn = 64, TEn = 256;
constexpr int NBLK = 64;   // recurrence blocks, 512 thr each -> 512 waves

// ---- workspace layout (bytes) ----
constexpr size_t OFF_ENCP = 0;                                          // (B*TE, H) f32
constexpr size_t OFF_ENCT = OFF_ENCP + (size_t)Bb*TEn*Hh*4;             // (B, H, TE) f32
constexpr size_t OFF_G0E  = OFF_ENCT + (size_t)Bb*Hh*TEn*4;             // (TD*B, 4H) f32
constexpr size_t OFF_FCWB = OFF_G0E  + (size_t)TDn*Bb*4*Hh*4;           // (NPAD, H) bf16
constexpr size_t OFF_H1B  = OFF_FCWB + (size_t)NPAD*Hh*2;               // (TD*B, H) bf16
constexpr size_t OFF_Q    = OFF_H1B  + (size_t)TDn*Bb*Hh*2;             // (B, H) f32
constexpr size_t OFF_SC   = OFF_Q    + (size_t)Bb*Hh*4;                 // (B, TE) f32
constexpr size_t OFF_CTX  = OFF_SC   + (size_t)Bb*TEn*4;                // (B, H) f32
constexpr size_t OFF_H0   = OFF_CTX  + (size_t)Bb*Hh*4;                 // 2x (B,H)
constexpr size_t OFF_H1   = OFF_H0   + (size_t)2*Bb*Hh*4;               // 2x (B,H)
constexpr size_t OFF_SYNC = OFF_H1   + (size_t)2*Bb*Hh*4;               // 20.5 KiB sync area
// sync layout: flagA @0 (64 lines x 128B), flagB @8192, grpA @16384, grpB @18432

DI float dot4(f32x4 a, f32x4 b) { return a[0]*b[0] + a[1]*b[1] + a[2]*b[2] + a[3]*b[3]; }
DI float wsum(float v) { for (int m = 32; m; m >>= 1) v += __shfl_xor(v, m, 64); return v; }
DI float wmax(float v) { for (int m = 32; m; m >>= 1) v = fmaxf(v, __shfl_xor(v, m, 64)); return v; }
DI float tanhfast(float x) { float e = __expf(2.f * x); return 1.f - 2.f / (e + 1.f); }
DI float sigm(float x) { return 1.f / (1.f + __expf(-x)); }

// ---- transpose-reduce: lane partials a[NV] (a[r] = partial of output r) ->
// butterfly halving; returns output r = (l & (NV-1)), fully summed across 64 lanes,
// present in ALL lanes. shfl count = NV-1 + log2(64/NV).
template<int NV>
DI float xreduce(float (&buf)[NV], const int l) {
    int cnt = NV;
    #pragma unroll
    for (int m = 1; m < NV; m <<= 1) {
        const bool hi = (l & m) != 0;
        #pragma unroll
        for (int i = 0; i < NV; ++i) {
            if (i < cnt / 2) {
                float x0 = buf[2*i], x1 = buf[2*i + 1];
                float send = hi ? x0 : x1;
                float keep = hi ? x1 : x0;
                float recv = __shfl_xor(send, m, 64);
                buf[i] = keep + recv;
            }
        }
        cnt >>= 1;
    }
    float v = buf[0];
    #pragma unroll
    for (int m = NV; m < 64; m <<= 1)
        v += __shfl_xor(v, m, 64);
    return v;
}

// LDS bank-quad spreading swizzle (dword index, preserves 16B blocks)
DI int swz(int a) { return a ^ (((a >> 5) & 7) << 2); }

// ---- agent-scope (device-coherent) data path for cross-block state ----
DI float gload1(const float* p) {
    return __hip_atomic_load(p, __ATOMIC_RELAXED, __HIP_MEMORY_SCOPE_AGENT);
}
DI void gstore1(float* p, float v) {
    __hip_atomic_store(p, v, __ATOMIC_RELAXED, __HIP_MEMORY_SCOPE_AGENT);
}
DI f32x2 gload2(const float* p) {
    unsigned long long u = __hip_atomic_load((const unsigned long long*)p,
                                             __ATOMIC_RELAXED, __HIP_MEMORY_SCOPE_AGENT);
    return __builtin_bit_cast(f32x2, u);
}
DI void gstore2(float* p, f32x2 v) {
    __hip_atomic_store((unsigned long long*)p, __builtin_bit_cast(unsigned long long, v),
                       __ATOMIC_RELAXED, __HIP_MEMORY_SCOPE_AGENT);
}
DI f32x4 gload4(const float* p) {
    f32x2 a = gload2(p), b = gload2(p + 2);
    f32x4 r; r[0] = a[0]; r[1] = a[1]; r[2] = b[0]; r[3] = b[1];
    return r;
}
DI void gstoreu16(unsigned short* p, unsigned short v) {
    __hip_atomic_store(p, v, __ATOMIC_RELAXED, __HIP_MEMORY_SCOPE_AGENT);
}

DI unsigned short f2bf(float f) {
    unsigned u = __builtin_bit_cast(unsigned, f);
    unsigned r = (u + 0x7FFFu + ((u >> 16) & 1u)) >> 16;
    return (unsigned short)r;
}
DI u16x8 cvt8(f32x4 a, f32x4 b) {
    u16x8 r;
    r[0]=f2bf(a[0]); r[1]=f2bf(a[1]); r[2]=f2bf(a[2]); r[3]=f2bf(a[3]);
    r[4]=f2bf(b[0]); r[5]=f2bf(b[1]); r[6]=f2bf(b[2]); r[7]=f2bf(b[3]);
    return r;
}

// ---- 2-hop grid barrier: 64 separate flag lines (u32 = kg); every block
// self-detects via one wave polling 64 lines with 64 lanes. Per-lane done-cache
// stops re-reading confirmed lines; s_sleep(32) (~0.85us) keeps poll pressure
// ~75 loads/us/line (r5's storm was ~30x this). Parity ping-pong arrays.
DI void gbar(char* sy, int bid, unsigned kg) {
    __syncthreads();   // compiler drains vmcnt per wave before s_barrier
    unsigned* fl = (unsigned*)(sy + ((kg & 1) ? 0 : 8192));
    const int tid = threadIdx.x;
    if (tid == 0) {
        asm volatile("s_waitcnt vmcnt(0)" ::: "memory");
        __hip_atomic_store(fl + (size_t)bid * 32, kg, __ATOMIC_RELAXED, __HIP_MEMORY_SCOPE_AGENT);
    }
    if (tid < 64) {
        bool done = false;
        for (;;) {
            if (!done)
                done = (__hip_atomic_load(fl + (size_t)tid * 32, __ATOMIC_RELAXED,
                                          __HIP_MEMORY_SCOPE_AGENT) == kg);
            if (__all(done)) break;
            __builtin_amdgcn_s_sleep(32);
        }
    }
    __syncthreads();
}

// ---- 4-block group barrier: one u32 word per group (same-XCD blocks) ----
DI void rbar(char* sy, int gb, int u4, unsigned kr) {
    __syncthreads();
    if (threadIdx.x == 0) {
        unsigned* w = (unsigned*)(sy + ((kr & 1) ? 16384 : 18432)) + (size_t)gb * 32;
        asm volatile("s_waitcnt vmcnt(0)" ::: "memory");
        __hip_atomic_store((char*)w + u4, (char)(unsigned char)kr, __ATOMIC_RELAXED,
                           __HIP_MEMORY_SCOPE_AGENT);
        const unsigned pat = 0x01010101u * (unsigned char)kr;
        while (__hip_atomic_load(w, __ATOMIC_RELAXED, __HIP_MEMORY_SCOPE_AGENT) != pat)
            __builtin_amdgcn_s_sleep(8);
    }
    __syncthreads();
}

// ---- prep: fc_w f32 -> bf16, padded to NPAD rows ----
__global__ void prep_fcw_kernel(const float* __restrict__ src, unsigned short* __restrict__ dst) {
    size_t i = ((size_t)blockIdx.x * 256 + threadIdx.x) << 3;
    int n = (int)(i >> 9);
    u16x8 v = {0,0,0,0,0,0,0,0};
    if (n < Vv) {
        const float* p = src + i;
        v = cvt8(*(const f32x4*)p, *(const f32x4*)(p + 4));
    }
    *(u16x8*)(dst + i) = v;
}

// ---- prep: enc (B,TE,H) -> encT (B,H,TE) ----
__global__ void transpose_kernel(const float* __restrict__ enc, float* __restrict__ encT) {
    __shared__ float tile[32][33];
    const int b = blockIdx.z, e0 = blockIdx.x << 5, h0 = blockIdx.y << 5;
    const int tx = threadIdx.x, ty = threadIdx.y;  // 32 x 8
    #pragma unroll
    for (int i = 0; i < 4; ++i)
        tile[ty + i*8][tx] = enc[((size_t)(b*TEn + e0 + ty + i*8))*Hh + h0 + tx];
    __syncthreads();
    #pragma unroll
    for (int i = 0; i < 4; ++i)
        encT[((size_t)(b*Hh + h0 + ty + i*8))*TEn + e0 + tx] = tile[tx][ty + i*8];
}

// ---- MFMA bf16 GEMM: C[m][n] = sum_k A[m][k]*B[n][k] (+bias), 128x128x32 tiles ----
template<int SRCBF, int GATHER, int OUTM>
__global__ __launch_bounds__(256, 2) void gemm_bt(
    const void* __restrict__ Av, const void* __restrict__ Bv,
    const float* __restrict__ bias, const float* __restrict__ bias2,
    float* __restrict__ Cout, int M, int N, int K, int ldb,
    const int* __restrict__ ids, int NV)
{
    __shared__ unsigned short As[128*32], Bs[128*32];
    const int tid = threadIdx.x;
    const int bn = blockIdx.x, bm = blockIdx.y;
    const int w = tid >> 6, l = tid & 63;
    const int wm = w >> 1, wn = w & 1;
    const int lr = l & 15, ls = l >> 4;
    f32x4 acc[4][4] = {};

    const int r0 = tid >> 2, c0 = (tid & 3) << 3;

    for (int kb = 0; kb < K; kb += 32) {
        #pragma unroll
        for (int half = 0; half < 2; ++half) {
            const int rr = r0 + half*64;
            {   // A tile
                const int gm = bm*128 + rr;
                size_t arow = GATHER ? (size_t)ids[((gm & 15) << 6) + (gm >> 4)] : (size_t)gm;
                u16x8 v;
                if (SRCBF) {
                    v = *(const u16x8*)((const unsigned short*)Av + arow*(size_t)K + kb + c0);
                } else {
                    const float* ap = (const float*)Av + arow*(size_t)K + kb + c0;
                    v = cvt8(*(const f32x4*)ap, *(const f32x4*)(ap + 4));
                }
                *(u16x8*)&As[rr*32 + c0] = v;
            }
            {   // B tile
                const size_t brow = (size_t)(bn*128 + rr);
                u16x8 v;
                if (SRCBF) {
                    v = *(const u16x8*)((const unsigned short*)Bv + brow*(size_t)ldb + kb + c0);
                } else {
                    const float* bp = (const float*)Bv + brow*(size_t)ldb + kb + c0;
                    v = cvt8(*(const f32x4*)bp, *(const f32x4*)(bp + 4));
                }
                *(u16x8*)&Bs[rr*32 + c0] = v;
            }
        }
        __syncthreads();
        bf16x8 af[4], bfv[4];
        #pragma unroll
        for (int mt = 0; mt < 4; ++mt) af[mt]  = *(const bf16x8*)&As[(wm*64 + mt*16 + lr)*32 + ls*8];
        #pragma unroll
        for (int nt = 0; nt < 4; ++nt) bfv[nt] = *(const bf16x8*)&Bs[(wn*64 + nt*16 + lr)*32 + ls*8];
        #pragma unroll
        for (int mt = 0; mt < 4; ++mt)
            #pragma unroll
            for (int nt = 0; nt < 4; ++nt)
                acc[mt][nt] = __builtin_amdgcn_mfma_f32_16x16x32_bf16(af[mt], bfv[nt], acc[mt][nt], 0, 0, 0);
        __syncthreads();
    }

    #pragma unroll
    for (int mt = 0; mt < 4; ++mt) {
        #pragma unroll
        for (int nt = 0; nt < 4; ++nt) {
            const int n = bn*128 + wn*64 + nt*16 + lr;
            const int mbase = bm*128 + wm*64 + mt*16 + ls*4;
            f32x4 a = acc[mt][nt];
            #pragma unroll
            for (int r = 0; r < 4; ++r) {
                const int m = mbase + r;
                if (OUTM == 0) {
                    float v = a[r] + bias[n] + (bias2 ? bias2[n] : 0.f);
                    Cout[(size_t)m*N + n] = v;
                } else {
                    if (n < NV) {
                        float v = a[r] + bias[n];
                        Cout[(size_t)(((m & 15) << 6) + (m >> 4))*NV + n] = v;
                    }
                }
            }
        }
    }
}

// ---- cooperative recurrence: 64 blocks x 512 thr ----
// j-phases (Q, L0, L1): wave j = bid*8+wid owns gate-row j, weights in VGPRs;
// per-phase reduction via transpose-reduce (xreduce), not per-output wsum.
// batch-phases (C scores, D softmax+ctx): group gb = bid&15 (same XCD), u4 = bid>>4.
// Schedule/step: Q -G- C -g- D -G- L0 -G- L1 -G-
__global__ __launch_bounds__(512, 2) void recur_kernel(
    const float* __restrict__ ih, const float* __restrict__ ic,
    const float* __restrict__ W2w, const float* __restrict__ W2b,
    const float* __restrict__ vw, const float* __restrict__ vb,
    const int* __restrict__ smask,
    const float* __restrict__ Wi0, const float* __restrict__ Wh0,
    const float* __restrict__ Wi1, const float* __restrict__ Wh1,
    const float* __restrict__ bi1, const float* __restrict__ bh1,
    char* __restrict__ ws)
{
    float* encP = (float*)(ws + OFF_ENCP);
    float* encT = (float*)(ws + OFF_ENCT);
    float* g0e  = (float*)(ws + OFF_G0E);
    unsigned short* h1bf = (unsigned short*)(ws + OFF_H1B);
    float* qb  = (float*)(ws + OFF_Q);
    float* sc  = (float*)(ws + OFF_SC);
    float* ctx = (float*)(ws + OFF_CTX);
    float* h0b = (float*)(ws + OFF_H0);
    float* h1v = (float*)(ws + OFF_H1);
    char* sy   = (char*)(ws + OFF_SYNC);

    __shared__ float lds[2 * Bb * Hh];   // 64 KiB staging

    const int tid = threadIdx.x, bid = blockIdx.x;
    const int wid = tid >> 6, l = tid & 63;
    const int j  = (bid << 3) + wid;     // owned gate-row, 0..511
    const int k0 = l << 3;               // lane k-slice (8 floats)

    // ---- persistent per-lane LSTM weight fragments ----
    f32x4 wi0a[4], wi0b[4], wh0a[4], wh0b[4];
    f32x4 wi1a[4], wi1b[4], wh1a[4], wh1b[4];
    float bb1[4];
    #pragma unroll
    for (int g = 0; g < 4; ++g) {
        const float* p0 = Wi0 + (size_t)(g*Hh + j)*(Ee + Hh) + Ee + k0;
        wi0a[g] = *(const f32x4*)p0; wi0b[g] = *(const f32x4*)(p0 + 4);
        const float* p1 = Wh0 + (size_t)(g*Hh + j)*Hh + k0;
        wh0a[g] = *(const f32x4*)p1; wh0b[g] = *(const f32x4*)(p1 + 4);
        const float* p2 = Wi1 + (size_t)(g*Hh + j)*Hh + k0;
        wi1a[g] = *(const f32x4*)p2; wi1b[g] = *(const f32x4*)(p2 + 4);
        const float* p3 = Wh1 + (size_t)(g*Hh + j)*Hh + k0;
        wh1a[g] = *(const f32x4*)p3; wh1b[g] = *(const f32x4*)(p3 + 4);
        bb1[g] = bi1[g*Hh + j] + bh1[g*Hh + j];   // wave-uniform
    }
    // t-invariant attention params
    const float* wr = W2w + (size_t)j*Hh + k0;
    const f32x4 w2a = *(const f32x4*)wr, w2d = *(const f32x4*)(wr + 4);
    const float w2bias = W2b[j];
    const f32x4 va = *(const f32x4*)&vw[k0], vd = *(const f32x4*)&vw[k0 + 4];
    const float vbias = vb[0];

    // cell state: lanes with (l&3)==0 && l<32 own batch b = (l>>2) [pass 0] and
    // b = 8+(l>>2) [pass 1] for column j.
    const bool cellLane = ((l & 3) == 0) && (l < 32);
    const int  bA = l >> 2;              // pass-0 batch for cell lanes
    float c0r[2], c1r[2];
    c0r[0] = cellLane ? ic[bA*Hh + j]              : 0.f;
    c0r[1] = cellLane ? ic[(8 + bA)*Hh + j]        : 0.f;
    c1r[0] = cellLane ? ic[Bb*Hh + bA*Hh + j]      : 0.f;
    c1r[1] = cellLane ? ic[Bb*Hh + (8 + bA)*Hh + j]: 0.f;

    // batch-phase mapping: group gb = bid&15 (4 blocks differing by 16 -> same XCD)
    const int gb  = bid & 15, u4 = bid >> 4;
    const int se0 = u4*64 + wid*8;        // 8 score rows per wave
    const int ch0 = u4*128 + wid*16;      // 16 ctx cols per wave
    const int msk = (l < 8) ? smask[gb*TEn + se0 + l] : 1;

    // init h double-buffers (parity 0)
    for (int i = (bid*512 + tid)*4; i < Bb*Hh; i += NBLK*512*4) {
        gstore2(&h0b[i],     *(const f32x2*)&ih[i]);
        gstore2(&h0b[i + 2], *(const f32x2*)&ih[i + 2]);
        gstore2(&h1v[i],     *(const f32x2*)&ih[Bb*Hh + i]);
        gstore2(&h1v[i + 2], *(const f32x2*)&ih[Bb*Hh + i + 2]);
    }
    unsigned kg = 1, kr = 0;
    gbar(sy, bid, kg);

    for (int t = 0; t < TDn; ++t) {
        const int p = t & 1;
        const float* h1r = h1v + p*(Bb*Hh);
        float*       h1w = h1v + (p^1)*(Bb*Hh);
        const float* h0r = h0b + p*(Bb*Hh);
        float*       h0w = h0b + (p^1)*(Bb*Hh);

        // prefetch this step's g0e gates for the cell lanes (hides under Q/C/D)
        float ge[2][4] = {};
        if (cellLane) {
            const float* gpA = g0e + ((size_t)(t*Bb + bA))*(4*Hh) + j;
            const float* gpB = g0e + ((size_t)(t*Bb + 8 + bA))*(4*Hh) + j;
            #pragma unroll
            for (int g = 0; g < 4; ++g) { ge[0][g] = gpA[(size_t)g*Hh]; ge[1][g] = gpB[(size_t)g*Hh]; }
        }

        // ===== phase Q (j-waves): q[b][j] = h1[b] . W2row_j + b2 =====
        {
            for (int i = tid*4; i < Bb*Hh; i += 2048)
                *(f32x4*)&lds[swz(i)] = gload4(&h1r[i]);
            __syncthreads();
            float a[16];
            #pragma unroll
            for (int b = 0; b < Bb; ++b) {
                f32x4 ha = *(const f32x4*)&lds[swz(b*Hh + k0)];
                f32x4 hd = *(const f32x4*)&lds[swz(b*Hh + k0 + 4)];
                a[b] = dot4(ha, w2a) + dot4(hd, w2d);
            }
            float qv = xreduce<16>(a, l) + w2bias;
            if (l < 16) gstore1(&qb[l*Hh + j], qv);
        }
        gbar(sy, bid, ++kg);

        // ===== phase C (batch group): scores for e in [u4*64, u4*64+64) =====
        {
            if (tid < 128) *(f32x4*)&lds[tid*4] = gload4(&qb[gb*Hh + tid*4]);
            __syncthreads();
            f32x4 qa = *(const f32x4*)&lds[k0];
            f32x4 qd = *(const f32x4*)&lds[k0 + 4];
            float a[8];
            #pragma unroll
            for (int i = 0; i < 8; ++i) {
                const float* ep = encP + ((size_t)(gb*TEn + se0 + i))*Hh + k0;
                f32x4 ea = *(const f32x4*)ep, ed = *(const f32x4*)(ep + 4);
                float s = 0.f;
                #pragma unroll
                for (int c = 0; c < 4; ++c)
                    s += tanhfast(ea[c] + qa[c]) * va[c] + tanhfast(ed[c] + qd[c]) * vd[c];
                a[i] = s;
            }
            float sv = xreduce<8>(a, l) + vbias;
            if (l < 8)
                gstore1(&sc[gb*TEn + se0 + l], (msk == 0) ? -1e9f : sv);
        }
        rbar(sy, gb, u4, ++kr);

        // ===== phase D (batch group): softmax (dup) + ctx cols [u4*128,+128) =====
        {
            f32x4 s4 = gload4(&sc[gb*TEn + (l << 2)]);
            float mx = wmax(fmaxf(fmaxf(s4[0], s4[1]), fmaxf(s4[2], s4[3])));
            f32x4 e4; float sm = 0.f;
            #pragma unroll
            for (int c = 0; c < 4; ++c) { e4[c] = __expf(s4[c] - mx); sm += e4[c]; }
            sm = wsum(sm);
            const float inv = 1.0f / sm;
            float a[16];
            #pragma unroll
            for (int i = 0; i < 16; ++i) {
                f32x4 en = *(const f32x4*)&encT[((size_t)(gb*Hh + ch0 + i))*TEn + (l << 2)];
                a[i] = dot4(e4, en);
            }
            float cv = xreduce<16>(a, l) * inv;
            if (l < 16) gstore1(&ctx[gb*Hh + ch0 + l], cv);
        }
        gbar(sy, bid, ++kg);

        // ===== phase L0 (j-waves): LSTM layer 0, transpose-reduce =====
        {
            for (int i = tid*4; i < Bb*Hh; i += 2048) {
                *(f32x4*)&lds[swz(i)]          = gload4(&ctx[i]);
                *(f32x4*)&lds[swz(Bb*Hh + i)]  = gload4(&h0r[i]);
            }
            __syncthreads();
            #pragma unroll
            for (int pass = 0; pass < 2; ++pass) {
                const int base = pass * 8;
                float acc[32];
                #pragma unroll
                for (int bb = 0; bb < 8; ++bb) {
                    const int b = base + bb;
                    f32x4 xa = *(const f32x4*)&lds[swz(b*Hh + k0)];
                    f32x4 xd = *(const f32x4*)&lds[swz(b*Hh + k0 + 4)];
                    f32x4 ha = *(const f32x4*)&lds[swz(Bb*Hh + b*Hh + k0)];
                    f32x4 hd = *(const f32x4*)&lds[swz(Bb*Hh + b*Hh + k0 + 4)];
                    #pragma unroll
                    for (int g = 0; g < 4; ++g)
                        acc[bb*4 + g] = dot4(wi0a[g],xa) + dot4(wi0b[g],xd)
                                      + dot4(wh0a[g],ha) + dot4(wh0b[g],hd);
                }
                float v  = xreduce<32>(acc, l);           // lane holds (g=l&3, bb=(l>>2)&7)
                float x1 = __shfl_xor(v, 1, 64);
                float x2 = __shfl_xor(v, 2, 64);
                float x3 = __shfl_xor(v, 3, 64);
                if (cellLane) {
                    const int b = base + bA;
                    float ii = sigm(v  + ge[pass][0]);
                    float ff = sigm(x1 + ge[pass][1]);
                    float gg = tanhfast(x2 + ge[pass][2]);
                    float oo = sigm(x3 + ge[pass][3]);
                    float cn = ff*c0r[pass] + ii*gg;
                    c0r[pass] = cn;
                    gstore1(&h0w[b*Hh + j], oo * tanhfast(cn));
                }
            }
        }
        gbar(sy, bid, ++kg);

        // ===== phase L1 (j-waves): LSTM layer 1 + bf16 h1 store =====
        {
            for (int i = tid*4; i < Bb*Hh; i += 2048) {
                *(f32x4*)&lds[swz(i)]          = gload4(&h0w[i]);
                *(f32x4*)&lds[swz(Bb*Hh + i)]  = gload4(&h1r[i]);
            }
            __syncthreads();
            #pragma unroll
            for (int pass = 0; pass < 2; ++pass) {
                const int base = pass * 8;
                float acc[32];
                #pragma unroll
                for (int bb = 0; bb < 8; ++bb) {
                    const int b = base + bb;
                    f32x4 xa = *(const f32x4*)&lds[swz(b*Hh + k0)];
                    f32x4 xd = *(const f32x4*)&lds[swz(b*Hh + k0 + 4)];
                    f32x4 ha = *(const f32x4*)&lds[swz(Bb*Hh + b*Hh + k0)];
                    f32x4 hd = *(const f32x4*)&lds[swz(Bb*Hh + b*Hh + k0 + 4)];
                    #pragma unroll
                    for (int g = 0; g < 4; ++g)
                        acc[bb*4 + g] = dot4(wi1a[g],xa) + dot4(wi1b[g],xd)
                                      + dot4(wh1a[g],ha) + dot4(wh1b[g],hd);
                }
                float v  = xreduce<32>(acc, l);
                float x1 = __shfl_xor(v, 1, 64);
                float x2 = __shfl_xor(v, 2, 64);
                float x3 = __shfl_xor(v, 3, 64);
                if (cellLane) {
                    const int b = base + bA;
                    float ii = sigm(v  + bb1[0]);
                    float ff = sigm(x1 + bb1[1]);
                    float gg = tanhfast(x2 + bb1[2]);
                    float oo = sigm(x3 + bb1[3]);
                    float cn = ff*c1r[pass] + ii*gg;
                    c1r[pass] = cn;
                    float hn = oo * tanhfast(cn);
                    gstore1(&h1w[b*Hh + j], hn);
                    gstoreu16(&h1bf[((size_t)(t*Bb + b))*Hh + j], f2bf(hn));
                }
            }
        }
        gbar(sy, bid, ++kg);
    }
}

extern "C" void kernel_launch(void* const* d_in, const int* in_sizes, int n_in,
                              void* d_out, int out_size, void* d_ws, size_t ws_size,
                              hipStream_t stream)
{
    const int*   ids  = (const int*)d_in[0];
    const float* ih   = (const float*)d_in[1];
    const float* ic   = (const float*)d_in[2];
    const float* enc  = (const float*)d_in[3];
    const int*   smask= (const int*)d_in[4];
    const float* emb  = (const float*)d_in[5];
    const float* W1w  = (const float*)d_in[6];
    const float* W1b  = (const float*)d_in[7];
    const float* W2w  = (const float*)d_in[8];
    const float* W2b  = (const float*)d_in[9];
    const float* vw   = (const float*)d_in[10];
    const float* vb   = (const float*)d_in[11];
    const float* Wi0  = (const float*)d_in[12];
    const float* Wh0  = (const float*)d_in[13];
    const float* bi0  = (const float*)d_in[14];
    const float* bh0  = (const float*)d_in[15];
    const float* Wi1  = (const float*)d_in[16];
    const float* Wh1  = (const float*)d_in[17];
    const float* bi1  = (const float*)d_in[18];
    const float* bh1  = (const float*)d_in[19];
    const float* fcw  = (const float*)d_in[20];
    const float* fcb  = (const float*)d_in[21];
    float* out = (float*)d_out;
    char*  ws  = (char*)d_ws;

    // flags must start at 0 (ws is poisoned 0xAA before timing)
    hipMemsetAsync(ws + OFF_SYNC, 0, 20480, stream);

    // prep: fc_w -> bf16 (padded)
    prep_fcw_kernel<<<dim3((unsigned)((size_t)NPAD*Hh/8/256)), dim3(256), 0, stream>>>(
        fcw, (unsigned short*)(ws + OFF_FCWB));

    // prep: enc transpose
    transpose_kernel<<<dim3(TEn/32, Hh/32, Bb), dim3(32, 8), 0, stream>>>(
        enc, (float*)(ws + OFF_ENCT));

    // enc_proj = enc @ W1^T + b1
    gemm_bt<0,0,0><<<dim3(Hh/128, (Bb*TEn)/128), dim3(256), 0, stream>>>(
        enc, W1w, W1b, nullptr, (float*)(ws + OFF_ENCP),
        Bb*TEn, Hh, Hh, Hh, nullptr, 0);

    // g0_emb = emb[ids] @ W_ih0[:, :E]^T + b_ih0 + b_hh0
    gemm_bt<0,1,0><<<dim3((4*Hh)/128, (TDn*Bb)/128), dim3(256), 0, stream>>>(
        emb, Wi0, bi0, bh0, (float*)(ws + OFF_G0E),
        TDn*Bb, 4*Hh, Ee, Ee + Hh, ids, 0);

    // sequential recurrence (cooperative, 64 blocks x 512 threads)
    {
        void* args[] = { (void*)&ih, (void*)&ic, (void*)&W2w, (void*)&W2b,
                         (void*)&vw, (void*)&vb, (void*)&smask,
                         (void*)&Wi0, (void*)&Wh0, (void*)&Wi1, (void*)&Wh1,
                         (void*)&bi1, (void*)&bh1, (void*)&ws };
        hipLaunchCooperativeKernel((void*)recur_kernel, dim3(NBLK), dim3(512), args, 0, stream);
    }

    // logits = h1_all @ fc_w^T + fc_b   (batched over all 64 steps)
    gemm_bt<1,0,1><<<dim3(NPAD/128, (TDn*Bb)/128), dim3(256), 0, stream>>>(
        ws + OFF_H1B, ws + OFF_FCWB, fcb, nullptr, out,
        TDn*Bb, NPAD, Hh, Hh, nullptr, Vv);
}